// Round 2
// baseline (130.200 us; speedup 1.0000x reference)
//
#include <hip/hip_runtime.h>
#include <hip/hip_bf16.h>

typedef unsigned short u16;
typedef __bf16 bf16x8 __attribute__((ext_vector_type(8)));
typedef float f32x4 __attribute__((ext_vector_type(4)));

#define DEVINL __device__ __forceinline__

static constexpr int Bc = 8, Tc = 2048;
// M = B*T = 16384 rows; DM=1024; DK=64; 192 total output cols (K|Q|V)

DEVINL u16 f2bf(float f) {
  unsigned u = __builtin_bit_cast(unsigned, f);
  unsigned r = u + 0x7fffu + ((u >> 16) & 1u);   // RNE
  return (u16)(r >> 16);
}
DEVINL float bf2f(u16 h) {
  unsigned u = ((unsigned)h) << 16;
  return __builtin_bit_cast(float, u);
}

// swizzled LDS read of 8 contiguous bf16 from a [R][64] bf16 tile.
// byte swizzle: byte ^= ((row&7)<<4)  -> in u16 units: col ^= ((row&7)<<3)
DEVINL bf16x8 lds_ld8(const u16* p, int row, int col) {
  return *(const bf16x8*)&p[row * 64 + (col ^ ((row & 7) << 3))];
}

// ---------------------------------------------------------------------------
// Kernel 0: wt_{hi,lo}[c][k] = split(W_{c/64}[k][c%64]), c in [0,192)
// ---------------------------------------------------------------------------
__global__ __launch_bounds__(256) void build_wt(const float* __restrict__ Wk,
                                                const float* __restrict__ Wq,
                                                const float* __restrict__ Wv,
                                                u16* __restrict__ wt_hi,
                                                u16* __restrict__ wt_lo) {
  int idx = blockIdx.x * 256 + threadIdx.x;      // 192*1024 = 196608
  int c = idx >> 10, k = idx & 1023;
  const float* W = (c < 64) ? Wk : (c < 128 ? Wq : Wv);
  float f = W[k * 64 + (c & 63)];
  u16 h = f2bf(f);
  wt_hi[idx] = h;
  wt_lo[idx] = f2bf(f - bf2f(h));
}

// ---------------------------------------------------------------------------
// Kernel 1: fused QKV projection, hi/lo-split bf16 (~fp32 accuracy).
// Grid 512 x 256 thr, 32 rows/block. q,k stored as hi/lo pairs; v single.
// ---------------------------------------------------------------------------
__global__ __launch_bounds__(256) void proj_kernel(const float* __restrict__ x,
                                                   const u16* __restrict__ wt_hi,
                                                   const u16* __restrict__ wt_lo,
                                                   u16* __restrict__ kb_h, u16* __restrict__ kb_l,
                                                   u16* __restrict__ qb_h, u16* __restrict__ qb_l,
                                                   u16* __restrict__ vb) {
  __shared__ u16 xh_l[32 * 64];
  __shared__ u16 xl_l[32 * 64];
  const int t = threadIdx.x;
  const int w = t >> 6, lane = t & 63;
  const int l16 = lane & 15, lhi = lane >> 4;
  const int rb = blockIdx.x * 32;
  const int cb = w * 48;                 // wave covers 48 of 192 cols
  const int sr = t >> 3, sc = (t & 7) * 8;

  f32x4 acc[2][3];
#pragma unroll
  for (int a = 0; a < 2; ++a)
#pragma unroll
    for (int c = 0; c < 3; ++c) acc[a][c] = (f32x4){0.f, 0.f, 0.f, 0.f};

  for (int ch = 0; ch < 16; ++ch) {      // K chunks of 64
    const float* src = x + (size_t)(rb + sr) * 1024 + ch * 64 + sc;
    f32x4 f0 = *(const f32x4*)src;
    f32x4 f1 = *(const f32x4*)(src + 4);
    union { u16 u[8]; uint4 v; } ph, pl;
#pragma unroll
    for (int j = 0; j < 4; ++j) {
      u16 h0 = f2bf(f0[j]); ph.u[j] = h0;     pl.u[j] = f2bf(f0[j] - bf2f(h0));
      u16 h1 = f2bf(f1[j]); ph.u[4 + j] = h1; pl.u[4 + j] = f2bf(f1[j] - bf2f(h1));
    }
    if (ch) __syncthreads();             // prev compute done before overwrite
    *(uint4*)&xh_l[sr * 64 + (sc ^ ((sr & 7) << 3))] = ph.v;
    *(uint4*)&xl_l[sr * 64 + (sc ^ ((sr & 7) << 3))] = pl.v;
    __syncthreads();

#pragma unroll
    for (int kk = 0; kk < 2; ++kk) {
      bf16x8 a0h = lds_ld8(xh_l, l16, kk * 32 + lhi * 8);
      bf16x8 a0l = lds_ld8(xl_l, l16, kk * 32 + lhi * 8);
      bf16x8 a1h = lds_ld8(xh_l, 16 + l16, kk * 32 + lhi * 8);
      bf16x8 a1l = lds_ld8(xl_l, 16 + l16, kk * 32 + lhi * 8);
      const size_t wo = (size_t)ch * 64 + kk * 32 + lhi * 8;
#pragma unroll
      for (int tc = 0; tc < 3; ++tc) {
        size_t wi = wo + (size_t)(cb + tc * 16 + l16) * 1024;
        bf16x8 bh = *(const bf16x8*)&wt_hi[wi];
        bf16x8 bl = *(const bf16x8*)&wt_lo[wi];
        acc[0][tc] = __builtin_amdgcn_mfma_f32_16x16x32_bf16(a0h, bh, acc[0][tc], 0, 0, 0);
        acc[0][tc] = __builtin_amdgcn_mfma_f32_16x16x32_bf16(a0h, bl, acc[0][tc], 0, 0, 0);
        acc[0][tc] = __builtin_amdgcn_mfma_f32_16x16x32_bf16(a0l, bh, acc[0][tc], 0, 0, 0);
        acc[1][tc] = __builtin_amdgcn_mfma_f32_16x16x32_bf16(a1h, bh, acc[1][tc], 0, 0, 0);
        acc[1][tc] = __builtin_amdgcn_mfma_f32_16x16x32_bf16(a1h, bl, acc[1][tc], 0, 0, 0);
        acc[1][tc] = __builtin_amdgcn_mfma_f32_16x16x32_bf16(a1l, bh, acc[1][tc], 0, 0, 0);
      }
    }
  }

  // epilogue: C frag row = (lane>>4)*4+i, col = lane&15
#pragma unroll
  for (int ri = 0; ri < 2; ++ri) {
#pragma unroll
    for (int tc = 0; tc < 3; ++tc) {
      int gc = cb + tc * 16 + l16;
      int cc = gc & 63;
      int row = rb + ri * 16 + lhi * 4;
#pragma unroll
      for (int i = 0; i < 4; ++i) {
        float f = acc[ri][tc][i];
        size_t off = (size_t)(row + i) * 64 + cc;
        u16 h = f2bf(f);
        if (gc < 64) {
          kb_h[off] = h; kb_l[off] = f2bf(f - bf2f(h));
        } else if (gc < 128) {
          qb_h[off] = h; qb_l[off] = f2bf(f - bf2f(h));
        } else {
          vb[off] = h;
        }
      }
    }
  }
}

// ---------------------------------------------------------------------------
// Kernel 2: causal flash attention, hi/lo-split QK^T. Grid 256 = 8 b x 32 qt.
// 4 waves x 16 q-rows. KV tiles of 64. Online softmax in fp32.
// ---------------------------------------------------------------------------
__global__ __launch_bounds__(256) void attn_kernel(const u16* __restrict__ qb_h,
                                                   const u16* __restrict__ qb_l,
                                                   const u16* __restrict__ kb_h,
                                                   const u16* __restrict__ kb_l,
                                                   const u16* __restrict__ vb,
                                                   float* __restrict__ out) {
  __shared__ u16 qh_l[64 * 64];
  __shared__ u16 ql_l[64 * 64];
  __shared__ u16 kh_l[64 * 64];
  __shared__ u16 kl_l[64 * 64];
  __shared__ u16 vt_l[64 * 64];          // transposed: [dk][kv], swizzled
  __shared__ u16 p_l[4 * 16 * 64];       // per-wave P tile, swizzled

  const int t = threadIdx.x, w = t >> 6, lane = t & 63;
  const int l16 = lane & 15, lhi = lane >> 4;
  const int b = blockIdx.x & 7, qt = blockIdx.x >> 3;
  const int qbase = qt * 64;
  const int sr = t >> 2, sc16 = (t & 3) * 16;
  const float NEG_INF = -3.0e38f;

  // stage Q tile hi/lo (swizzled)
  {
    size_t go = (size_t)(b * 2048 + qbase + sr) * 64 + sc16;
    const uint4* sh = (const uint4*)(qb_h + go);
    const uint4* sl = (const uint4*)(qb_l + go);
    int d0 = sr * 64 + ((sc16) ^ ((sr & 7) << 3));
    int d1 = sr * 64 + ((sc16 + 8) ^ ((sr & 7) << 3));
    *(uint4*)&qh_l[d0] = sh[0]; *(uint4*)&qh_l[d1] = sh[1];
    *(uint4*)&ql_l[d0] = sl[0]; *(uint4*)&ql_l[d1] = sl[1];
  }
  __syncthreads();
  bf16x8 aq0h = lds_ld8(qh_l, w * 16 + l16, lhi * 8);
  bf16x8 aq1h = lds_ld8(qh_l, w * 16 + l16, 32 + lhi * 8);
  bf16x8 aq0l = lds_ld8(ql_l, w * 16 + l16, lhi * 8);
  bf16x8 aq1l = lds_ld8(ql_l, w * 16 + l16, 32 + lhi * 8);

  f32x4 o[4];
  float m_r[4], l_r[4];
#pragma unroll
  for (int i = 0; i < 4; ++i) { o[i] = (f32x4){0.f, 0.f, 0.f, 0.f}; m_r[i] = NEG_INF; l_r[i] = 0.f; }

  for (int tk = 0; tk <= qt; ++tk) {
    // load K(hi/lo),V tile from global first (overlaps previous compute)
    size_t go = (size_t)(b * 2048 + tk * 64 + sr) * 64 + sc16;
    uint4 kh0 = *(const uint4*)(kb_h + go);
    uint4 kh1 = *(const uint4*)(kb_h + go + 8);
    uint4 kl0 = *(const uint4*)(kb_l + go);
    uint4 kl1 = *(const uint4*)(kb_l + go + 8);
    union { uint4 v; u16 u[8]; } v0, v1;
    v0.v = *(const uint4*)(vb + go);
    v1.v = *(const uint4*)(vb + go + 8);

    if (tk) __syncthreads();             // prev tile's reads done
    int d0 = sr * 64 + ((sc16) ^ ((sr & 7) << 3));
    int d1 = sr * 64 + ((sc16 + 8) ^ ((sr & 7) << 3));
    *(uint4*)&kh_l[d0] = kh0; *(uint4*)&kh_l[d1] = kh1;
    *(uint4*)&kl_l[d0] = kl0; *(uint4*)&kl_l[d1] = kl1;
#pragma unroll
    for (int j = 0; j < 8; ++j) {        // V transpose scatter
      int c0 = sc16 + j, c1 = sc16 + 8 + j;
      vt_l[c0 * 64 + (sr ^ ((c0 & 7) << 3))] = v0.u[j];
      vt_l[c1 * 64 + (sr ^ ((c1 & 7) << 3))] = v1.u[j];
    }
    __syncthreads();

    // S = Q K^T  (per wave: 16 rows x 64 kv), hi*hi + hi*lo + lo*hi
    f32x4 sa[4];
#pragma unroll
    for (int t4 = 0; t4 < 4; ++t4) sa[t4] = (f32x4){0.f, 0.f, 0.f, 0.f};
#pragma unroll
    for (int t4 = 0; t4 < 4; ++t4) {
      bf16x8 bk0h = lds_ld8(kh_l, t4 * 16 + l16, lhi * 8);
      bf16x8 bk0l = lds_ld8(kl_l, t4 * 16 + l16, lhi * 8);
      bf16x8 bk1h = lds_ld8(kh_l, t4 * 16 + l16, 32 + lhi * 8);
      bf16x8 bk1l = lds_ld8(kl_l, t4 * 16 + l16, 32 + lhi * 8);
      sa[t4] = __builtin_amdgcn_mfma_f32_16x16x32_bf16(aq0h, bk0h, sa[t4], 0, 0, 0);
      sa[t4] = __builtin_amdgcn_mfma_f32_16x16x32_bf16(aq0h, bk0l, sa[t4], 0, 0, 0);
      sa[t4] = __builtin_amdgcn_mfma_f32_16x16x32_bf16(aq0l, bk0h, sa[t4], 0, 0, 0);
      sa[t4] = __builtin_amdgcn_mfma_f32_16x16x32_bf16(aq1h, bk1h, sa[t4], 0, 0, 0);
      sa[t4] = __builtin_amdgcn_mfma_f32_16x16x32_bf16(aq1h, bk1l, sa[t4], 0, 0, 0);
      sa[t4] = __builtin_amdgcn_mfma_f32_16x16x32_bf16(aq1l, bk1h, sa[t4], 0, 0, 0);
    }

    // causal mask on diagonal tile (tile-local indices; tiles are aligned)
    const int rw = w * 16 + lhi * 4;     // row-in-tile base
    if (tk == qt) {
#pragma unroll
      for (int t4 = 0; t4 < 4; ++t4) {
        int col = t4 * 16 + l16;
#pragma unroll
        for (int i = 0; i < 4; ++i)
          if (col > rw + i) sa[t4][i] = -1e30f;
      }
    }

    // online softmax (row r held by 16 lanes of group lhi; reduce via shfl_xor)
    float pf[4][4];
#pragma unroll
    for (int i = 0; i < 4; ++i) {
      float tm = fmaxf(fmaxf(sa[0][i], sa[1][i]), fmaxf(sa[2][i], sa[3][i]));
#pragma unroll
      for (int d = 1; d < 16; d <<= 1) tm = fmaxf(tm, __shfl_xor(tm, d));
      float mn = fmaxf(m_r[i], tm);
      float scl = __expf(m_r[i] - mn);
      float rs = 0.f;
#pragma unroll
      for (int t4 = 0; t4 < 4; ++t4) {
        float p = __expf(sa[t4][i] - mn);
        pf[t4][i] = p;
        rs += p;
      }
#pragma unroll
      for (int d = 1; d < 16; d <<= 1) rs += __shfl_xor(rs, d);
      l_r[i] = l_r[i] * scl + rs;
      m_r[i] = mn;
#pragma unroll
      for (int t4 = 0; t4 < 4; ++t4) o[t4][i] *= scl;
    }

    // P -> bf16 -> per-wave LDS (swizzled), then PV
    u16* pw = p_l + w * 1024;
#pragma unroll
    for (int i = 0; i < 4; ++i) {
      int rr = lhi * 4 + i;
#pragma unroll
      for (int t4 = 0; t4 < 4; ++t4) {
        int col = t4 * 16 + l16;
        pw[rr * 64 + (col ^ ((rr & 7) << 3))] = f2bf(pf[t4][i]);
      }
    }
#pragma unroll
    for (int kk = 0; kk < 2; ++kk) {
      bf16x8 ap = lds_ld8(pw, l16, kk * 32 + lhi * 8);
#pragma unroll
      for (int t4 = 0; t4 < 4; ++t4) {
        bf16x8 bv = lds_ld8(vt_l, t4 * 16 + l16, kk * 32 + lhi * 8);
        o[t4] = __builtin_amdgcn_mfma_f32_16x16x32_bf16(ap, bv, o[t4], 0, 0, 0);
      }
    }
  }

  // epilogue: out fp32 = o / l
  float* og = out + (size_t)(b * 2048 + qbase + w * 16) * 64;
#pragma unroll
  for (int t4 = 0; t4 < 4; ++t4) {
    int col = t4 * 16 + l16;
#pragma unroll
    for (int i = 0; i < 4; ++i)
      og[(size_t)(lhi * 4 + i) * 64 + col] = o[t4][i] / l_r[i];
  }
}

// ---------------------------------------------------------------------------
extern "C" void kernel_launch(void* const* d_in, const int* in_sizes, int n_in,
                              void* d_out, int out_size, void* d_ws, size_t ws_size,
                              hipStream_t stream) {
  const float* x  = (const float*)d_in[0];
  const float* Wk = (const float*)d_in[1];
  const float* Wq = (const float*)d_in[2];
  const float* Wv = (const float*)d_in[3];
  float* out = (float*)d_out;

  const size_t QKV = (size_t)Bc * Tc * 64;      // 1,048,576 elems each
  u16* kb_h = (u16*)d_ws;
  u16* kb_l = kb_h + QKV;
  u16* qb_h = kb_l + QKV;
  u16* qb_l = qb_h + QKV;
  u16* vb   = qb_l + QKV;
  u16* wt_h = vb + QKV;                         // 192*1024
  u16* wt_l = wt_h + (size_t)192 * 1024;

  build_wt<<<768, 256, 0, stream>>>(Wk, Wq, Wv, wt_h, wt_l);
  proj_kernel<<<512, 256, 0, stream>>>(x, wt_h, wt_l, kb_h, kb_l, qb_h, qb_l, vb);
  attn_kernel<<<256, 256, 0, stream>>>(qb_h, qb_l, kb_h, kb_l, vb, out);
}

// Round 3
// 127.681 us; speedup vs baseline: 1.0197x; 1.0197x over previous
//
#include <hip/hip_runtime.h>
#include <hip/hip_bf16.h>

typedef unsigned short u16;
typedef __bf16 bf16x8 __attribute__((ext_vector_type(8)));
typedef float f32x4 __attribute__((ext_vector_type(4)));

#define DEVINL __device__ __forceinline__

static constexpr int Bc = 8, Tc = 2048;

DEVINL u16 f2bf(float f) {
  unsigned u = __builtin_bit_cast(unsigned, f);
  unsigned r = u + 0x7fffu + ((u >> 16) & 1u);   // RNE
  return (u16)(r >> 16);
}
DEVINL float bf2f(u16 h) {
  unsigned u = ((unsigned)h) << 16;
  return __builtin_bit_cast(float, u);
}

// swizzled LDS read of 8 contiguous bf16 from a [R][64] bf16 tile.
DEVINL bf16x8 lds_ld8(const u16* p, int row, int col) {
  return *(const bf16x8*)&p[row * 64 + (col ^ ((row & 7) << 3))];
}

// ---------------------------------------------------------------------------
// Kernel 0: wt_{hi,lo}[c][k] = split(W_{c/64}[k][c%64]), c in [0,192)
// ---------------------------------------------------------------------------
__global__ __launch_bounds__(256) void build_wt(const float* __restrict__ Wk,
                                                const float* __restrict__ Wq,
                                                const float* __restrict__ Wv,
                                                u16* __restrict__ wt_hi,
                                                u16* __restrict__ wt_lo) {
  int idx = blockIdx.x * 256 + threadIdx.x;      // 192*1024
  int c = idx >> 10, k = idx & 1023;
  const float* W = (c < 64) ? Wk : (c < 128 ? Wq : Wv);
  float f = W[k * 64 + (c & 63)];
  u16 h = f2bf(f);
  wt_hi[idx] = h;
  wt_lo[idx] = f2bf(f - bf2f(h));
}

// ---------------------------------------------------------------------------
// Kernel 1: fused QKV projection, hi/lo split, 2-deep x prefetch + LDS dbuf.
// Grid 512 x 256 thr, 32 rows/block.
// ---------------------------------------------------------------------------
__global__ __launch_bounds__(256) void proj_kernel(const float* __restrict__ x,
                                                   const u16* __restrict__ wt_hi,
                                                   const u16* __restrict__ wt_lo,
                                                   u16* __restrict__ kb_h, u16* __restrict__ kb_l,
                                                   u16* __restrict__ qb_h, u16* __restrict__ qb_l,
                                                   u16* __restrict__ vb) {
  __shared__ u16 xh[2][32 * 64];
  __shared__ u16 xl[2][32 * 64];
  const int t = threadIdx.x;
  const int w = t >> 6, lane = t & 63;
  const int l16 = lane & 15, lhi = lane >> 4;
  const int rb = blockIdx.x * 32;
  const int cb = w * 48;
  const int sr = t >> 3, sc = (t & 7) * 8;
  const float* xrow = x + (size_t)(rb + sr) * 1024 + sc;

  f32x4 acc[2][3];
#pragma unroll
  for (int a = 0; a < 2; ++a)
#pragma unroll
    for (int c = 0; c < 3; ++c) acc[a][c] = (f32x4){0.f, 0.f, 0.f, 0.f};

#define CVT_STORE(S, F0, F1)                                                   \
  {                                                                            \
    union { u16 u[8]; uint4 v; } ph_, pl_;                                     \
    _Pragma("unroll") for (int j = 0; j < 4; ++j) {                            \
      u16 h0 = f2bf((F0)[j]); ph_.u[j] = h0; pl_.u[j] = f2bf((F0)[j] - bf2f(h0)); \
      u16 h1 = f2bf((F1)[j]); ph_.u[4+j] = h1; pl_.u[4+j] = f2bf((F1)[j] - bf2f(h1)); \
    }                                                                          \
    *(uint4*)&xh[S][sr * 64 + (sc ^ ((sr & 7) << 3))] = ph_.v;                 \
    *(uint4*)&xl[S][sr * 64 + (sc ^ ((sr & 7) << 3))] = pl_.v;                 \
  }

#define COMPUTE(S, CH)                                                         \
  _Pragma("unroll") for (int kk = 0; kk < 2; ++kk) {                           \
    bf16x8 a0h = lds_ld8(xh[S], l16, kk * 32 + lhi * 8);                       \
    bf16x8 a0l = lds_ld8(xl[S], l16, kk * 32 + lhi * 8);                       \
    bf16x8 a1h = lds_ld8(xh[S], 16 + l16, kk * 32 + lhi * 8);                  \
    bf16x8 a1l = lds_ld8(xl[S], 16 + l16, kk * 32 + lhi * 8);                  \
    _Pragma("unroll") for (int tc = 0; tc < 3; ++tc) {                         \
      size_t wi = (size_t)(cb + tc * 16 + l16) * 1024 + (CH) * 64 + kk * 32 + lhi * 8; \
      bf16x8 bh = *(const bf16x8*)&wt_hi[wi];                                  \
      bf16x8 bl = *(const bf16x8*)&wt_lo[wi];                                  \
      acc[0][tc] = __builtin_amdgcn_mfma_f32_16x16x32_bf16(a0h, bh, acc[0][tc], 0, 0, 0); \
      acc[0][tc] = __builtin_amdgcn_mfma_f32_16x16x32_bf16(a0h, bl, acc[0][tc], 0, 0, 0); \
      acc[0][tc] = __builtin_amdgcn_mfma_f32_16x16x32_bf16(a0l, bh, acc[0][tc], 0, 0, 0); \
      acc[1][tc] = __builtin_amdgcn_mfma_f32_16x16x32_bf16(a1h, bh, acc[1][tc], 0, 0, 0); \
      acc[1][tc] = __builtin_amdgcn_mfma_f32_16x16x32_bf16(a1h, bl, acc[1][tc], 0, 0, 0); \
      acc[1][tc] = __builtin_amdgcn_mfma_f32_16x16x32_bf16(a1l, bh, acc[1][tc], 0, 0, 0); \
    }                                                                          \
  }

  // prologue: 2-deep prefetch
  f32x4 A0 = *(const f32x4*)(xrow);
  f32x4 A1 = *(const f32x4*)(xrow + 4);
  f32x4 B0 = *(const f32x4*)(xrow + 64);
  f32x4 B1 = *(const f32x4*)(xrow + 64 + 4);
  CVT_STORE(0, A0, A1);
  __syncthreads();

  for (int i = 0; i < 8; ++i) {
    const int ch = 2 * i;
    if (ch + 2 < 16) { A0 = *(const f32x4*)(xrow + (ch + 2) * 64); A1 = *(const f32x4*)(xrow + (ch + 2) * 64 + 4); }
    COMPUTE(0, ch);
    CVT_STORE(1, B0, B1);
    __syncthreads();
    if (ch + 3 < 16) { B0 = *(const f32x4*)(xrow + (ch + 3) * 64); B1 = *(const f32x4*)(xrow + (ch + 3) * 64 + 4); }
    COMPUTE(1, ch + 1);
    if (ch + 2 < 16) { CVT_STORE(0, A0, A1); __syncthreads(); }
  }
#undef CVT_STORE
#undef COMPUTE

  // epilogue
#pragma unroll
  for (int ri = 0; ri < 2; ++ri) {
#pragma unroll
    for (int tc = 0; tc < 3; ++tc) {
      int gc = cb + tc * 16 + l16;
      int cc = gc & 63;
      int row = rb + ri * 16 + lhi * 4;
#pragma unroll
      for (int i = 0; i < 4; ++i) {
        float f = acc[ri][tc][i];
        size_t off = (size_t)(row + i) * 64 + cc;
        u16 h = f2bf(f);
        if (gc < 64)       { kb_h[off] = h; kb_l[off] = f2bf(f - bf2f(h)); }
        else if (gc < 128) { qb_h[off] = h; qb_l[off] = f2bf(f - bf2f(h)); }
        else               { vb[off] = h; }
      }
    }
  }
}

// ---------------------------------------------------------------------------
// Kernel 2: causal flash attention, 32-row q-tiles, 2 waves, grid 512.
// Longest blocks dispatched first; batch pinned to XCD via bid&7.
// ---------------------------------------------------------------------------
__global__ __launch_bounds__(128) void attn_kernel(const u16* __restrict__ qb_h,
                                                   const u16* __restrict__ qb_l,
                                                   const u16* __restrict__ kb_h,
                                                   const u16* __restrict__ kb_l,
                                                   const u16* __restrict__ vb,
                                                   float* __restrict__ out) {
  __shared__ u16 qh_l[32 * 64];
  __shared__ u16 ql_l[32 * 64];
  __shared__ u16 kh_l[64 * 64];
  __shared__ u16 kl_l[64 * 64];
  __shared__ u16 vt_l[64 * 64];          // transposed: [dk][kv], swizzled
  __shared__ u16 p_l[2 * 16 * 64];       // per-wave P tile, swizzled

  const int t = threadIdx.x, w = t >> 6, lane = t & 63;
  const int l16 = lane & 15, lhi = lane >> 4;
  const int b = blockIdx.x & 7;
  const int j = 63 - (blockIdx.x >> 3);  // 0..63, longest first
  const int qbase = j * 32;
  const int nt = (j >> 1) + 1;
  const int dlim = (j & 1) << 5;
  const float NEG_INF = -3.0e38f;

  // stage Q tile hi/lo (swizzled): thread -> row t>>2, col (t&3)*16
  {
    const int qr = t >> 2, qc = (t & 3) * 16;
    size_t go = (size_t)(b * 2048 + qbase + qr) * 64 + qc;
    int d0 = qr * 64 + (qc ^ ((qr & 7) << 3));
    int d1 = qr * 64 + ((qc + 8) ^ ((qr & 7) << 3));
    *(uint4*)&qh_l[d0] = *(const uint4*)(qb_h + go);
    *(uint4*)&qh_l[d1] = *(const uint4*)(qb_h + go + 8);
    *(uint4*)&ql_l[d0] = *(const uint4*)(qb_l + go);
    *(uint4*)&ql_l[d1] = *(const uint4*)(qb_l + go + 8);
  }
  __syncthreads();
  bf16x8 aq0h = lds_ld8(qh_l, w * 16 + l16, lhi * 8);
  bf16x8 aq1h = lds_ld8(qh_l, w * 16 + l16, 32 + lhi * 8);
  bf16x8 aq0l = lds_ld8(ql_l, w * 16 + l16, lhi * 8);
  bf16x8 aq1l = lds_ld8(ql_l, w * 16 + l16, 32 + lhi * 8);

  f32x4 o[4];
  float m_r[4], l_r[4];
#pragma unroll
  for (int i = 0; i < 4; ++i) { o[i] = (f32x4){0.f, 0.f, 0.f, 0.f}; m_r[i] = NEG_INF; l_r[i] = 0.f; }

  const int sr = t >> 1, sc = (t & 1) * 32;   // staging: row sr, 32 cols

  for (int tk = 0; tk < nt; ++tk) {
    size_t go = (size_t)(b * 2048 + tk * 64 + sr) * 64 + sc;
    uint4 kh0 = *(const uint4*)(kb_h + go);
    uint4 kh1 = *(const uint4*)(kb_h + go + 8);
    uint4 kh2 = *(const uint4*)(kb_h + go + 16);
    uint4 kh3 = *(const uint4*)(kb_h + go + 24);
    uint4 kl0 = *(const uint4*)(kb_l + go);
    uint4 kl1 = *(const uint4*)(kb_l + go + 8);
    uint4 kl2 = *(const uint4*)(kb_l + go + 16);
    uint4 kl3 = *(const uint4*)(kb_l + go + 24);
    union { uint4 v; u16 u[8]; } v0, v1, v2, v3;
    v0.v = *(const uint4*)(vb + go);
    v1.v = *(const uint4*)(vb + go + 8);
    v2.v = *(const uint4*)(vb + go + 16);
    v3.v = *(const uint4*)(vb + go + 24);

    if (tk) __syncthreads();             // prev tile's reads done
    {
      int sw = (sr & 7) << 3;
      *(uint4*)&kh_l[sr * 64 + ((sc)      ^ sw)] = kh0;
      *(uint4*)&kh_l[sr * 64 + ((sc + 8)  ^ sw)] = kh1;
      *(uint4*)&kh_l[sr * 64 + ((sc + 16) ^ sw)] = kh2;
      *(uint4*)&kh_l[sr * 64 + ((sc + 24) ^ sw)] = kh3;
      *(uint4*)&kl_l[sr * 64 + ((sc)      ^ sw)] = kl0;
      *(uint4*)&kl_l[sr * 64 + ((sc + 8)  ^ sw)] = kl1;
      *(uint4*)&kl_l[sr * 64 + ((sc + 16) ^ sw)] = kl2;
      *(uint4*)&kl_l[sr * 64 + ((sc + 24) ^ sw)] = kl3;
    }
#pragma unroll
    for (int jj = 0; jj < 8; ++jj) {     // V transpose scatter
      int c0 = sc + jj, c1 = sc + 8 + jj, c2 = sc + 16 + jj, c3 = sc + 24 + jj;
      vt_l[c0 * 64 + (sr ^ ((c0 & 7) << 3))] = v0.u[jj];
      vt_l[c1 * 64 + (sr ^ ((c1 & 7) << 3))] = v1.u[jj];
      vt_l[c2 * 64 + (sr ^ ((c2 & 7) << 3))] = v2.u[jj];
      vt_l[c3 * 64 + (sr ^ ((c3 & 7) << 3))] = v3.u[jj];
    }
    __syncthreads();

    // S = Q K^T (per wave: 16 rows x 64 kv), hi*hi + hi*lo + lo*hi
    f32x4 sa[4];
#pragma unroll
    for (int t4 = 0; t4 < 4; ++t4) sa[t4] = (f32x4){0.f, 0.f, 0.f, 0.f};
#pragma unroll
    for (int t4 = 0; t4 < 4; ++t4) {
      bf16x8 bk0h = lds_ld8(kh_l, t4 * 16 + l16, lhi * 8);
      bf16x8 bk0l = lds_ld8(kl_l, t4 * 16 + l16, lhi * 8);
      bf16x8 bk1h = lds_ld8(kh_l, t4 * 16 + l16, 32 + lhi * 8);
      bf16x8 bk1l = lds_ld8(kl_l, t4 * 16 + l16, 32 + lhi * 8);
      sa[t4] = __builtin_amdgcn_mfma_f32_16x16x32_bf16(aq0h, bk0h, sa[t4], 0, 0, 0);
      sa[t4] = __builtin_amdgcn_mfma_f32_16x16x32_bf16(aq0h, bk0l, sa[t4], 0, 0, 0);
      sa[t4] = __builtin_amdgcn_mfma_f32_16x16x32_bf16(aq0l, bk0h, sa[t4], 0, 0, 0);
      sa[t4] = __builtin_amdgcn_mfma_f32_16x16x32_bf16(aq1h, bk1h, sa[t4], 0, 0, 0);
      sa[t4] = __builtin_amdgcn_mfma_f32_16x16x32_bf16(aq1h, bk1l, sa[t4], 0, 0, 0);
      sa[t4] = __builtin_amdgcn_mfma_f32_16x16x32_bf16(aq1l, bk1h, sa[t4], 0, 0, 0);
    }

    // causal mask on last tile: mask if col > dlim + local_row
    const int rw = w * 16 + lhi * 4;
    if (tk == nt - 1) {
#pragma unroll
      for (int t4 = 0; t4 < 4; ++t4) {
        int col = t4 * 16 + l16;
#pragma unroll
        for (int i = 0; i < 4; ++i)
          if (col > dlim + rw + i) sa[t4][i] = -1e30f;
      }
    }

    // online softmax
    float pf[4][4];
#pragma unroll
    for (int i = 0; i < 4; ++i) {
      float tm = fmaxf(fmaxf(sa[0][i], sa[1][i]), fmaxf(sa[2][i], sa[3][i]));
#pragma unroll
      for (int d = 1; d < 16; d <<= 1) tm = fmaxf(tm, __shfl_xor(tm, d));
      float mn = fmaxf(m_r[i], tm);
      float scl = __expf(m_r[i] - mn);
      float rs = 0.f;
#pragma unroll
      for (int t4 = 0; t4 < 4; ++t4) {
        float p = __expf(sa[t4][i] - mn);
        pf[t4][i] = p;
        rs += p;
      }
#pragma unroll
      for (int d = 1; d < 16; d <<= 1) rs += __shfl_xor(rs, d);
      l_r[i] = l_r[i] * scl + rs;
      m_r[i] = mn;
#pragma unroll
      for (int t4 = 0; t4 < 4; ++t4) o[t4][i] *= scl;
    }

    // P -> bf16 -> per-wave LDS (swizzled), then PV
    u16* pw = p_l + w * 1024;
#pragma unroll
    for (int i = 0; i < 4; ++i) {
      int rr = lhi * 4 + i;
#pragma unroll
      for (int t4 = 0; t4 < 4; ++t4) {
        int col = t4 * 16 + l16;
        pw[rr * 64 + (col ^ ((rr & 7) << 3))] = f2bf(pf[t4][i]);
      }
    }
#pragma unroll
    for (int kk = 0; kk < 2; ++kk) {
      bf16x8 ap = lds_ld8(pw, l16, kk * 32 + lhi * 8);
#pragma unroll
      for (int t4 = 0; t4 < 4; ++t4) {
        bf16x8 bv = lds_ld8(vt_l, t4 * 16 + l16, kk * 32 + lhi * 8);
        o[t4] = __builtin_amdgcn_mfma_f32_16x16x32_bf16(ap, bv, o[t4], 0, 0, 0);
      }
    }
  }

  // epilogue: out fp32 = o / l
  float* og = out + (size_t)(b * 2048 + qbase + w * 16) * 64;
#pragma unroll
  for (int t4 = 0; t4 < 4; ++t4) {
    int col = t4 * 16 + l16;
#pragma unroll
    for (int i = 0; i < 4; ++i)
      og[(size_t)(lhi * 4 + i) * 64 + col] = o[t4][i] / l_r[i];
  }
}

// ---------------------------------------------------------------------------
extern "C" void kernel_launch(void* const* d_in, const int* in_sizes, int n_in,
                              void* d_out, int out_size, void* d_ws, size_t ws_size,
                              hipStream_t stream) {
  const float* x  = (const float*)d_in[0];
  const float* Wk = (const float*)d_in[1];
  const float* Wq = (const float*)d_in[2];
  const float* Wv = (const float*)d_in[3];
  float* out = (float*)d_out;

  const size_t QKV = (size_t)Bc * Tc * 64;
  u16* kb_h = (u16*)d_ws;
  u16* kb_l = kb_h + QKV;
  u16* qb_h = kb_l + QKV;
  u16* qb_l = qb_h + QKV;
  u16* vb   = qb_l + QKV;
  u16* wt_h = vb + QKV;
  u16* wt_l = wt_h + (size_t)192 * 1024;

  build_wt<<<768, 256, 0, stream>>>(Wk, Wq, Wv, wt_h, wt_l);
  proj_kernel<<<512, 256, 0, stream>>>(x, wt_h, wt_l, kb_h, kb_l, qb_h, qb_l, vb);
  attn_kernel<<<512, 128, 0, stream>>>(qb_h, qb_l, kb_h, kb_l, vb, out);
}

// Round 4
// 114.213 us; speedup vs baseline: 1.1400x; 1.1179x over previous
//
#include <hip/hip_runtime.h>
#include <hip/hip_bf16.h>

typedef unsigned short u16;
typedef __bf16 bf16x8 __attribute__((ext_vector_type(8)));
typedef float f32x4 __attribute__((ext_vector_type(4)));

#define DEVINL __device__ __forceinline__

static constexpr int Bc = 8, Tc = 2048;

DEVINL u16 f2bf(float f) {
  unsigned u = __builtin_bit_cast(unsigned, f);
  unsigned r = u + 0x7fffu + ((u >> 16) & 1u);   // RNE
  return (u16)(r >> 16);
}
DEVINL float bf2f(u16 h) {
  unsigned u = ((unsigned)h) << 16;
  return __builtin_bit_cast(float, u);
}

// swizzled LDS read of 8 contiguous bf16 from a [R][64] bf16 tile.
DEVINL bf16x8 lds_ld8(const u16* p, int row, int col) {
  return *(const bf16x8*)&p[row * 64 + (col ^ ((row & 7) << 3))];
}

// ---------------------------------------------------------------------------
// Kernel 0: wt_{hi,lo}[c][k] = split(W_{c/64}[k][c%64]), c in [0,192)
// ---------------------------------------------------------------------------
__global__ __launch_bounds__(256) void build_wt(const float* __restrict__ Wk,
                                                const float* __restrict__ Wq,
                                                const float* __restrict__ Wv,
                                                u16* __restrict__ wt_hi,
                                                u16* __restrict__ wt_lo) {
  int idx = blockIdx.x * 256 + threadIdx.x;      // 192*1024
  int c = idx >> 10, k = idx & 1023;
  const float* W = (c < 64) ? Wk : (c < 128 ? Wq : Wv);
  float f = W[k * 64 + (c & 63)];
  u16 h = f2bf(f);
  wt_hi[idx] = h;
  wt_lo[idx] = f2bf(f - bf2f(h));
}

// ---------------------------------------------------------------------------
// Kernel 1: fused QKV projection, hi/lo split, 2-deep x prefetch + LDS dbuf.
// Grid 512 x 256 thr, 32 rows/block. V written TRANSPOSED [b][d][t].
// ---------------------------------------------------------------------------
__global__ __launch_bounds__(256) void proj_kernel(const float* __restrict__ x,
                                                   const u16* __restrict__ wt_hi,
                                                   const u16* __restrict__ wt_lo,
                                                   u16* __restrict__ kb_h, u16* __restrict__ kb_l,
                                                   u16* __restrict__ qb_h, u16* __restrict__ qb_l,
                                                   u16* __restrict__ vt) {
  __shared__ u16 xh[2][32 * 64];
  __shared__ u16 xl[2][32 * 64];
  const int t = threadIdx.x;
  const int w = t >> 6, lane = t & 63;
  const int l16 = lane & 15, lhi = lane >> 4;
  const int rb = blockIdx.x * 32;
  const int cb = w * 48;
  const int sr = t >> 3, sc = (t & 7) * 8;
  const float* xrow = x + (size_t)(rb + sr) * 1024 + sc;

  f32x4 acc[2][3];
#pragma unroll
  for (int a = 0; a < 2; ++a)
#pragma unroll
    for (int c = 0; c < 3; ++c) acc[a][c] = (f32x4){0.f, 0.f, 0.f, 0.f};

#define CVT_STORE(S, F0, F1)                                                   \
  {                                                                            \
    union { u16 u[8]; uint4 v; } ph_, pl_;                                     \
    _Pragma("unroll") for (int j = 0; j < 4; ++j) {                            \
      u16 h0 = f2bf((F0)[j]); ph_.u[j] = h0; pl_.u[j] = f2bf((F0)[j] - bf2f(h0)); \
      u16 h1 = f2bf((F1)[j]); ph_.u[4+j] = h1; pl_.u[4+j] = f2bf((F1)[j] - bf2f(h1)); \
    }                                                                          \
    *(uint4*)&xh[S][sr * 64 + (sc ^ ((sr & 7) << 3))] = ph_.v;                 \
    *(uint4*)&xl[S][sr * 64 + (sc ^ ((sr & 7) << 3))] = pl_.v;                 \
  }

#define COMPUTE(S, CH)                                                         \
  _Pragma("unroll") for (int kk = 0; kk < 2; ++kk) {                           \
    bf16x8 a0h = lds_ld8(xh[S], l16, kk * 32 + lhi * 8);                       \
    bf16x8 a0l = lds_ld8(xl[S], l16, kk * 32 + lhi * 8);                       \
    bf16x8 a1h = lds_ld8(xh[S], 16 + l16, kk * 32 + lhi * 8);                  \
    bf16x8 a1l = lds_ld8(xl[S], 16 + l16, kk * 32 + lhi * 8);                  \
    _Pragma("unroll") for (int tc = 0; tc < 3; ++tc) {                         \
      size_t wi = (size_t)(cb + tc * 16 + l16) * 1024 + (CH) * 64 + kk * 32 + lhi * 8; \
      bf16x8 bh = *(const bf16x8*)&wt_hi[wi];                                  \
      bf16x8 bl = *(const bf16x8*)&wt_lo[wi];                                  \
      acc[0][tc] = __builtin_amdgcn_mfma_f32_16x16x32_bf16(a0h, bh, acc[0][tc], 0, 0, 0); \
      acc[0][tc] = __builtin_amdgcn_mfma_f32_16x16x32_bf16(a0h, bl, acc[0][tc], 0, 0, 0); \
      acc[0][tc] = __builtin_amdgcn_mfma_f32_16x16x32_bf16(a0l, bh, acc[0][tc], 0, 0, 0); \
      acc[1][tc] = __builtin_amdgcn_mfma_f32_16x16x32_bf16(a1h, bh, acc[1][tc], 0, 0, 0); \
      acc[1][tc] = __builtin_amdgcn_mfma_f32_16x16x32_bf16(a1h, bl, acc[1][tc], 0, 0, 0); \
      acc[1][tc] = __builtin_amdgcn_mfma_f32_16x16x32_bf16(a1l, bh, acc[1][tc], 0, 0, 0); \
    }                                                                          \
  }

  // prologue: 2-deep prefetch
  f32x4 A0 = *(const f32x4*)(xrow);
  f32x4 A1 = *(const f32x4*)(xrow + 4);
  f32x4 B0 = *(const f32x4*)(xrow + 64);
  f32x4 B1 = *(const f32x4*)(xrow + 64 + 4);
  CVT_STORE(0, A0, A1);
  __syncthreads();

  for (int i = 0; i < 8; ++i) {
    const int ch = 2 * i;
    if (ch + 2 < 16) { A0 = *(const f32x4*)(xrow + (ch + 2) * 64); A1 = *(const f32x4*)(xrow + (ch + 2) * 64 + 4); }
    COMPUTE(0, ch);
    CVT_STORE(1, B0, B1);
    __syncthreads();
    if (ch + 3 < 16) { B0 = *(const f32x4*)(xrow + (ch + 3) * 64); B1 = *(const f32x4*)(xrow + (ch + 3) * 64 + 4); }
    COMPUTE(1, ch + 1);
    if (ch + 2 < 16) { CVT_STORE(0, A0, A1); __syncthreads(); }
  }
#undef CVT_STORE
#undef COMPUTE

  // epilogue
#pragma unroll
  for (int ri = 0; ri < 2; ++ri) {
#pragma unroll
    for (int tc = 0; tc < 3; ++tc) {
      int gc = cb + tc * 16 + l16;
      int cc = gc & 63;
      int row = rb + ri * 16 + lhi * 4;
#pragma unroll
      for (int i = 0; i < 4; ++i) {
        float f = acc[ri][tc][i];
        int r = row + i;
        u16 h = f2bf(f);
        if (gc < 64) {
          size_t off = (size_t)r * 64 + cc;
          kb_h[off] = h; kb_l[off] = f2bf(f - bf2f(h));
        } else if (gc < 128) {
          size_t off = (size_t)r * 64 + cc;
          qb_h[off] = h; qb_l[off] = f2bf(f - bf2f(h));
        } else {
          int bb = r >> 11, tp = r & 2047;
          vt[((size_t)bb * 64 + cc) * 2048 + tp] = h;
        }
      }
    }
  }
}

// ---------------------------------------------------------------------------
// Kernel 2: causal flash attention, barrier-free. 1 wave/block, 32 q-rows.
// KV-split at 1024 (flash-decoding): 96 units x 8 batches = 768 blocks.
// Q/K/V^T fragments read directly from global (L2-resident per batch).
// Units with j>=32 write (O,m,l) partials; combine_kernel merges.
// ---------------------------------------------------------------------------
__global__ __launch_bounds__(64) void attn_kernel(const u16* __restrict__ qb_h,
                                                  const u16* __restrict__ qb_l,
                                                  const u16* __restrict__ kb_h,
                                                  const u16* __restrict__ kb_l,
                                                  const u16* __restrict__ vt,
                                                  float* __restrict__ out,
                                                  float* __restrict__ po,
                                                  float* __restrict__ pml) {
  __shared__ u16 p_l[2][1024];           // per-rowset P tile (16x64, swizzled)

  const int t = threadIdx.x;             // one wave
  const int l16 = t & 15, lhi = t >> 4;
  const int u = blockIdx.x >> 3, b = blockIdx.x & 7;

  int j, c;
  if (u < 32) { j = 32 + u; c = 0; }     // nt=16 units first (longest-first)
  else {
    int k = u - 32;
    int jp = 31 - (k >> 1);
    if (k & 1) { j = jp + 32; c = 1; } else { j = jp; c = 0; }
  }
  const int kv0 = c << 10;
  const int prefix = j * 32 + 32;
  const int kv_end = (prefix < kv0 + 1024) ? prefix : (kv0 + 1024);
  const int nt = (kv_end - kv0 + 63) >> 6;
  const bool diag = (kv_end == prefix);
  const bool split = (j >= 32);

  const size_t qrow = (size_t)b * 2048 + j * 32;

  // Q fragments straight from global: lane l16 = q row, 16B contiguous cols
  bf16x8 aqh[2][2], aql[2][2];           // [rowset][kk]
#pragma unroll
  for (int rs = 0; rs < 2; ++rs)
#pragma unroll
    for (int kk = 0; kk < 2; ++kk) {
      size_t qo = (qrow + rs * 16 + l16) * 64 + kk * 32 + lhi * 8;
      aqh[rs][kk] = *(const bf16x8*)(qb_h + qo);
      aql[rs][kk] = *(const bf16x8*)(qb_l + qo);
    }

  f32x4 o[2][4];
  float m_r[2][4], l_r[2][4];
#pragma unroll
  for (int rs = 0; rs < 2; ++rs)
#pragma unroll
    for (int i = 0; i < 4; ++i) {
      o[rs][i] = (f32x4){0.f, 0.f, 0.f, 0.f};
      m_r[rs][i] = -3.0e38f; l_r[rs][i] = 0.f;
    }

  for (int tk = 0; tk < nt; ++tk) {
    const int kvb = kv0 + tk * 64;
    const size_t kbase = ((size_t)b * 2048 + kvb) * 64;

    // issue all global fragment loads up front (independent; L2-resident)
    bf16x8 kh[4][2], kl[4][2], vv[4][2];
#pragma unroll
    for (int t4 = 0; t4 < 4; ++t4) {
      size_t kr = kbase + (size_t)(t4 * 16 + l16) * 64 + lhi * 8;
#pragma unroll
      for (int kk = 0; kk < 2; ++kk) {
        kh[t4][kk] = *(const bf16x8*)(kb_h + kr + kk * 32);
        kl[t4][kk] = *(const bf16x8*)(kb_l + kr + kk * 32);
      }
      size_t vr = ((size_t)b * 64 + t4 * 16 + l16) * 2048 + kvb + lhi * 8;
#pragma unroll
      for (int kk = 0; kk < 2; ++kk)
        vv[t4][kk] = *(const bf16x8*)(vt + vr + kk * 32);
    }

    // S = Q K^T, hi*hi + hi*lo + lo*hi
    f32x4 sa[2][4];
#pragma unroll
    for (int rs = 0; rs < 2; ++rs)
#pragma unroll
      for (int t4 = 0; t4 < 4; ++t4) {
        f32x4 s = (f32x4){0.f, 0.f, 0.f, 0.f};
        s = __builtin_amdgcn_mfma_f32_16x16x32_bf16(aqh[rs][0], kh[t4][0], s, 0, 0, 0);
        s = __builtin_amdgcn_mfma_f32_16x16x32_bf16(aqh[rs][0], kl[t4][0], s, 0, 0, 0);
        s = __builtin_amdgcn_mfma_f32_16x16x32_bf16(aql[rs][0], kh[t4][0], s, 0, 0, 0);
        s = __builtin_amdgcn_mfma_f32_16x16x32_bf16(aqh[rs][1], kh[t4][1], s, 0, 0, 0);
        s = __builtin_amdgcn_mfma_f32_16x16x32_bf16(aqh[rs][1], kl[t4][1], s, 0, 0, 0);
        s = __builtin_amdgcn_mfma_f32_16x16x32_bf16(aql[rs][1], kh[t4][1], s, 0, 0, 0);
        sa[rs][t4] = s;
      }

    // causal mask (global indices); only the diagonal unit's last tile
    if (diag && tk == nt - 1) {
#pragma unroll
      for (int rs = 0; rs < 2; ++rs) {
        int qr = j * 32 + rs * 16 + lhi * 4;
#pragma unroll
        for (int t4 = 0; t4 < 4; ++t4) {
          int col = kvb + t4 * 16 + l16;
#pragma unroll
          for (int i = 0; i < 4; ++i)
            if (col > qr + i) sa[rs][t4][i] = -1e30f;
        }
      }
    }

#pragma unroll
    for (int rs = 0; rs < 2; ++rs) {
      // online softmax
      float pf[4][4];
#pragma unroll
      for (int i = 0; i < 4; ++i) {
        float tm = fmaxf(fmaxf(sa[rs][0][i], sa[rs][1][i]), fmaxf(sa[rs][2][i], sa[rs][3][i]));
#pragma unroll
        for (int d = 1; d < 16; d <<= 1) tm = fmaxf(tm, __shfl_xor(tm, d));
        float mn = fmaxf(m_r[rs][i], tm);
        float scl = __expf(m_r[rs][i] - mn);
        float rsum = 0.f;
#pragma unroll
        for (int t4 = 0; t4 < 4; ++t4) {
          float p = __expf(sa[rs][t4][i] - mn);
          pf[t4][i] = p;
          rsum += p;
        }
#pragma unroll
        for (int d = 1; d < 16; d <<= 1) rsum += __shfl_xor(rsum, d);
        l_r[rs][i] = l_r[rs][i] * scl + rsum;
        m_r[rs][i] = mn;
#pragma unroll
        for (int t4 = 0; t4 < 4; ++t4) o[rs][t4][i] *= scl;
      }

      // P -> bf16 -> per-rowset LDS (swizzled, wave-private, no barrier)
      u16* pw = (u16*)p_l[rs];
#pragma unroll
      for (int i = 0; i < 4; ++i) {
        int rr = lhi * 4 + i;
#pragma unroll
        for (int t4 = 0; t4 < 4; ++t4) {
          int col = t4 * 16 + l16;
          pw[rr * 64 + (col ^ ((rr & 7) << 3))] = f2bf(pf[t4][i]);
        }
      }
      // PV
#pragma unroll
      for (int kk = 0; kk < 2; ++kk) {
        bf16x8 ap = lds_ld8(pw, l16, kk * 32 + lhi * 8);
#pragma unroll
        for (int t4 = 0; t4 < 4; ++t4)
          o[rs][t4] = __builtin_amdgcn_mfma_f32_16x16x32_bf16(ap, vv[t4][kk], o[rs][t4], 0, 0, 0);
      }
    }
  }

  if (!split) {
    float* og = out + qrow * 64;
#pragma unroll
    for (int rs = 0; rs < 2; ++rs)
#pragma unroll
      for (int t4 = 0; t4 < 4; ++t4) {
        int col = t4 * 16 + l16;
#pragma unroll
        for (int i = 0; i < 4; ++i)
          og[(size_t)(rs * 16 + lhi * 4 + i) * 64 + col] = o[rs][t4][i] / l_r[rs][i];
      }
  } else {
    int unit = ((j - 32) * 8 + b) * 2 + c;
    float* pou = po + (size_t)unit * 2048;
#pragma unroll
    for (int rs = 0; rs < 2; ++rs)
#pragma unroll
      for (int t4 = 0; t4 < 4; ++t4) {
        int col = t4 * 16 + l16;
#pragma unroll
        for (int i = 0; i < 4; ++i)
          pou[(rs * 16 + lhi * 4 + i) * 64 + col] = o[rs][t4][i];
      }
    if (l16 == 0) {
#pragma unroll
      for (int rs = 0; rs < 2; ++rs)
#pragma unroll
        for (int i = 0; i < 4; ++i) {
          int r = rs * 16 + lhi * 4 + i;
          pml[unit * 64 + r]      = m_r[rs][i];
          pml[unit * 64 + 32 + r] = l_r[rs][i];
        }
    }
  }
}

// ---------------------------------------------------------------------------
// Kernel 3: merge the two KV-chunk partials for j >= 32.
// Grid 256 = 8 b x 32 sj, 256 thr.
// ---------------------------------------------------------------------------
__global__ __launch_bounds__(256) void combine_kernel(const float* __restrict__ po,
                                                      const float* __restrict__ pml,
                                                      float* __restrict__ out) {
  const int b = blockIdx.x & 7, sj = blockIdx.x >> 3;
  const int j = sj + 32;
  const int u0 = (sj * 8 + b) * 2, u1 = u0 + 1;
  const float* p0 = po + (size_t)u0 * 2048;
  const float* p1 = po + (size_t)u1 * 2048;
  float* og = out + ((size_t)b * 2048 + j * 32) * 64;
#pragma unroll
  for (int k = 0; k < 8; ++k) {
    int e = k * 256 + threadIdx.x;
    int r = e >> 6;
    float m1 = pml[u0 * 64 + r], l1 = pml[u0 * 64 + 32 + r];
    float m2 = pml[u1 * 64 + r], l2 = pml[u1 * 64 + 32 + r];
    float M = fmaxf(m1, m2);
    float a1 = __expf(m1 - M), a2 = __expf(m2 - M);
    og[e] = (p0[e] * a1 + p1[e] * a2) / (l1 * a1 + l2 * a2);
  }
}

// ---------------------------------------------------------------------------
extern "C" void kernel_launch(void* const* d_in, const int* in_sizes, int n_in,
                              void* d_out, int out_size, void* d_ws, size_t ws_size,
                              hipStream_t stream) {
  const float* x  = (const float*)d_in[0];
  const float* Wk = (const float*)d_in[1];
  const float* Wq = (const float*)d_in[2];
  const float* Wv = (const float*)d_in[3];
  float* out = (float*)d_out;

  const size_t QKV = (size_t)Bc * Tc * 64;       // 1,048,576 elems
  char* w = (char*)d_ws;
  u16* kb_h = (u16*)w;               w += QKV * 2;
  u16* kb_l = (u16*)w;               w += QKV * 2;
  u16* qb_h = (u16*)w;               w += QKV * 2;
  u16* qb_l = (u16*)w;               w += QKV * 2;
  u16* vt   = (u16*)w;               w += QKV * 2;
  u16* wt_h = (u16*)w;               w += (size_t)192 * 1024 * 2;
  u16* wt_l = (u16*)w;               w += (size_t)192 * 1024 * 2;
  float* po = (float*)w;             w += (size_t)512 * 2048 * 4;
  float* pml = (float*)w;            w += (size_t)512 * 64 * 4;

  build_wt<<<768, 256, 0, stream>>>(Wk, Wq, Wv, wt_h, wt_l);
  proj_kernel<<<512, 256, 0, stream>>>(x, wt_h, wt_l, kb_h, kb_l, qb_h, qb_l, vt);
  attn_kernel<<<768, 64, 0, stream>>>(qb_h, qb_l, kb_h, kb_l, vt, out, po, pml);
  combine_kernel<<<256, 256, 0, stream>>>(po, pml, out);
}